// Round 7
// baseline (2238.552 us; speedup 1.0000x reference)
//
#include <hip/hip_runtime.h>
#include <hip/hip_fp16.h>
#include <stdint.h>

#define T_STEPS 1024
#define HDIM    128
#define NT      512   // threads per block = 4*H gate rows

// ---- packed f16-pair types --------------------------------------------------
typedef _Float16 v2h  __attribute__((ext_vector_type(2)));
typedef unsigned int u16x __attribute__((ext_vector_type(16)));  // 16 f16-pairs

union HU { uint32_t u; v2h v; };

// d = a0*b0 + a1*b1 + c  (f16 inputs, f32 accumulate) -> v_dot2_f32_f16
__device__ __forceinline__ float dot2h(uint32_t a, uint32_t b, float c) {
    HU ua, ub; ua.u = a; ub.u = b;
    return __builtin_amdgcn_fdot2(ua.v, ub.v, c, false);
}

__device__ __forceinline__ uint32_t packh2f(float2 e) {
    return (uint32_t)__half_as_ushort(__float2half_rn(e.x)) |
           ((uint32_t)__half_as_ushort(__float2half_rn(e.y)) << 16);
}
__device__ __forceinline__ uint16_t f2h(float f) {
    return __half_as_ushort(__float2half_rn(f));
}
__device__ __forceinline__ float sigmoidf_(float x) {
    return 1.0f / (1.0f + __expf(-x));
}
__device__ __forceinline__ float tanhf_(float x) {
    return 1.0f - 2.0f / (__expf(2.0f * x) + 1.0f);
}

// ===== AGPR stash ============================================================
// R0-R5: the toolchain caps ARCH VGPRs at pool/2-blocks (128 @ 512thr) and
// spills the weight set -> ~74 GB/dispatch scratch reloads at the L2 ceiling
// = the whole 2 ms. Escape hatch: the ACCUMULATOR file. Inline asm with
// explicit a<N> clobbers FORCES allocation (asm can't be spilled away);
// agpr_count is set from the clobbers. w2 -> a0..a63, w3 -> a64..a127.
#define WR_(n, e) asm volatile("v_accvgpr_write_b32 a" #n ", %0" :: "v"(e) : "a" #n)
#define WR(n, e)  WR_(n, e)
// volatile so the loop-invariant reads are NOT hoisted out of the t-loop
// (hoisting would put 128 dwords back into arch VGPRs -> spill).
#define RD_(n, d) asm volatile("v_accvgpr_read_b32 %0, a" #n : "=v"(d))
#define RD(n, d)  RD_(n, d)

#define LW2(n)     WR(n, packh2f(r2[n]))
#define LW3(n, m)  WR(n, packh2f(r3[m]))

// Load quarter q (16 f16-pairs) of a weight row into a named ext-vector SSA
// value (w1 lives in arch VGPRs: 64 dwords + ~40 working set fits the 128 cap).
#define SETW(W, rowptr, q) do {                                            \
    const float2* _r = ((const float2*)(rowptr)) + 16 * (q);               \
    W[0]  = packh2f(_r[0]);  W[1]  = packh2f(_r[1]);                       \
    W[2]  = packh2f(_r[2]);  W[3]  = packh2f(_r[3]);                       \
    W[4]  = packh2f(_r[4]);  W[5]  = packh2f(_r[5]);                       \
    W[6]  = packh2f(_r[6]);  W[7]  = packh2f(_r[7]);                       \
    W[8]  = packh2f(_r[8]);  W[9]  = packh2f(_r[9]);                       \
    W[10] = packh2f(_r[10]); W[11] = packh2f(_r[11]);                      \
    W[12] = packh2f(_r[12]); W[13] = packh2f(_r[13]);                      \
    W[14] = packh2f(_r[14]); W[15] = packh2f(_r[15]);                      \
} while (0)

#define DOT_Q(W, Hv, q, acc) do {                                          \
    uint4 _p0 = (Hv)[4*(q)+0], _p1 = (Hv)[4*(q)+1];                        \
    uint4 _p2 = (Hv)[4*(q)+2], _p3 = (Hv)[4*(q)+3];                        \
    acc = dot2h(W[0],  _p0.x, acc); acc = dot2h(W[1],  _p0.y, acc);        \
    acc = dot2h(W[2],  _p0.z, acc); acc = dot2h(W[3],  _p0.w, acc);        \
    acc = dot2h(W[4],  _p1.x, acc); acc = dot2h(W[5],  _p1.y, acc);        \
    acc = dot2h(W[6],  _p1.z, acc); acc = dot2h(W[7],  _p1.w, acc);        \
    acc = dot2h(W[8],  _p2.x, acc); acc = dot2h(W[9],  _p2.y, acc);        \
    acc = dot2h(W[10], _p2.z, acc); acc = dot2h(W[11], _p2.w, acc);        \
    acc = dot2h(W[12], _p3.x, acc); acc = dot2h(W[13], _p3.y, acc);        \
    acc = dot2h(W[14], _p3.z, acc); acc = dot2h(W[15], _p3.w, acc);        \
} while (0)

// Phase-2 block j: w2 dwords 4j..4j+3 (a A0..A3) dotted with h1 chunk j,
// w3 dwords (a B0..B3) dotted with h2 chunk j, all into ACC.
#define P2(j, A0,A1,A2,A3, B0,B1,B2,B3, ACC) do {                          \
    uint4 _p = Hv1[j]; uint4 _q = Hv2[j];                                  \
    uint32_t _u0,_u1,_u2,_u3,_v0,_v1,_v2,_v3;                              \
    RD(A0,_u0); RD(A1,_u1); RD(A2,_u2); RD(A3,_u3);                        \
    RD(B0,_v0); RD(B1,_v1); RD(B2,_v2); RD(B3,_v3);                        \
    ACC = dot2h(_u0, _p.x, ACC); ACC = dot2h(_u1, _p.y, ACC);              \
    ACC = dot2h(_u2, _p.z, ACC); ACC = dot2h(_u3, _p.w, ACC);              \
    ACC = dot2h(_v0, _q.x, ACC); ACC = dot2h(_v1, _q.y, ACC);              \
    ACC = dot2h(_v2, _q.z, ACC); ACC = dot2h(_v3, _q.w, ACC);              \
} while (0)

__global__ __launch_bounds__(NT) void lstm_persistent(
    const float* __restrict__ x,
    const float* __restrict__ W_ih1, const float* __restrict__ W_hh1,
    const float* __restrict__ b_ih1, const float* __restrict__ b_hh1,
    const float* __restrict__ W_ih2, const float* __restrict__ W_hh2,
    const float* __restrict__ b_ih2, const float* __restrict__ b_hh2,
    const float* __restrict__ W_out, const float* __restrict__ b_out,
    float* __restrict__ out)
{
    const int b   = blockIdx.x;    // sample
    const int tid = threadIdx.x;   // gate row 0..511

    __shared__ __align__(16) uint32_t h1p[HDIM / 2];  // h1 as f16 pairs
    __shared__ __align__(16) uint32_t h2p[HDIM / 2];  // h2 as f16 pairs
    __shared__ float gact[NT];                        // activated gates
    __shared__ float h2f[HDIM];                       // fp32 h2 for output dot

    // ---- w1 (layer-1 recurrent row) in arch VGPRs
    u16x w1a, w1b, w1c, w1d;
    {
        const float* r1 = W_hh1 + tid * HDIM;
        SETW(w1a, r1, 0); SETW(w1b, r1, 1); SETW(w1c, r1, 2); SETW(w1d, r1, 3);
    }
    // ---- w2 -> a0..a63, w3 -> a64..a127 (AGPR stash, once)
    {
        const float2* r2 = (const float2*)(W_ih2 + tid * HDIM);
        const float2* r3 = (const float2*)(W_hh2 + tid * HDIM);
        LW2(0);  LW2(1);  LW2(2);  LW2(3);  LW2(4);  LW2(5);  LW2(6);  LW2(7);
        LW2(8);  LW2(9);  LW2(10); LW2(11); LW2(12); LW2(13); LW2(14); LW2(15);
        LW2(16); LW2(17); LW2(18); LW2(19); LW2(20); LW2(21); LW2(22); LW2(23);
        LW2(24); LW2(25); LW2(26); LW2(27); LW2(28); LW2(29); LW2(30); LW2(31);
        LW2(32); LW2(33); LW2(34); LW2(35); LW2(36); LW2(37); LW2(38); LW2(39);
        LW2(40); LW2(41); LW2(42); LW2(43); LW2(44); LW2(45); LW2(46); LW2(47);
        LW2(48); LW2(49); LW2(50); LW2(51); LW2(52); LW2(53); LW2(54); LW2(55);
        LW2(56); LW2(57); LW2(58); LW2(59); LW2(60); LW2(61); LW2(62); LW2(63);
        LW3(64,0);   LW3(65,1);   LW3(66,2);   LW3(67,3);
        LW3(68,4);   LW3(69,5);   LW3(70,6);   LW3(71,7);
        LW3(72,8);   LW3(73,9);   LW3(74,10);  LW3(75,11);
        LW3(76,12);  LW3(77,13);  LW3(78,14);  LW3(79,15);
        LW3(80,16);  LW3(81,17);  LW3(82,18);  LW3(83,19);
        LW3(84,20);  LW3(85,21);  LW3(86,22);  LW3(87,23);
        LW3(88,24);  LW3(89,25);  LW3(90,26);  LW3(91,27);
        LW3(92,28);  LW3(93,29);  LW3(94,30);  LW3(95,31);
        LW3(96,32);  LW3(97,33);  LW3(98,34);  LW3(99,35);
        LW3(100,36); LW3(101,37); LW3(102,38); LW3(103,39);
        LW3(104,40); LW3(105,41); LW3(106,42); LW3(107,43);
        LW3(108,44); LW3(109,45); LW3(110,46); LW3(111,47);
        LW3(112,48); LW3(113,49); LW3(114,50); LW3(115,51);
        LW3(116,52); LW3(117,53); LW3(118,54); LW3(119,55);
        LW3(120,56); LW3(121,57); LW3(122,58); LW3(123,59);
        LW3(124,60); LW3(125,61); LW3(126,62); LW3(127,63);
    }
    const float bias1 = b_ih1[tid] + b_hh1[tid];
    const float bias2 = b_ih2[tid] + b_hh2[tid];
    const float wih1  = W_ih1[tid];
    const int   sec   = tid >> 7;   // 0:i 1:f 2:g 3:o
    float wo0 = 0.f, wo1 = 0.f;
    if (tid < 64) { wo0 = W_out[tid]; wo1 = W_out[tid + 64]; }
    const float bo = b_out[0];

    float c1 = 0.f, c2 = 0.f;       // live in threads 0..127

    if (tid < HDIM / 2) { h1p[tid] = 0u; h2p[tid] = 0u; }
    __syncthreads();

    const float* xb = x + b * T_STEPS;
    float*       ob = out + b * T_STEPS;
    float x_cur = xb[0];

    for (int t = 0; t < T_STEPS; t++) {
        float x_nxt = xb[(t + 1 < T_STEPS) ? (t + 1) : t];

        // ---------- phase 1: layer-1 gate preactivation (w1 in arch regs)
        const uint4* Hv1 = (const uint4*)h1p;
        float aA = fmaf(x_cur, wih1, bias1), aB = 0.f, aC = 0.f, aD = 0.f;
        DOT_Q(w1a, Hv1, 0, aA); DOT_Q(w1b, Hv1, 1, aB);
        DOT_Q(w1c, Hv1, 2, aC); DOT_Q(w1d, Hv1, 3, aD);
        float a1 = (aA + aB) + (aC + aD);
        gact[tid] = (sec == 2) ? tanhf_(a1) : sigmoidf_(a1);
        __syncthreads();   // barrier 1

        // ---------- layer-1 state update (threads 0..127)
        if (tid < HDIM) {
            float gi = gact[tid], gf = gact[tid + 128];
            float gg = gact[tid + 256], go = gact[tid + 384];
            c1 = fmaf(gf, c1, gi * gg);
            float h1 = go * tanhf_(c1);
            ((uint16_t*)h1p)[tid] = f2h(h1);
        }
        __syncthreads();   // barrier 2

        // ---------- phase 2: layer-2 gate preactivation (w2,w3 from AGPRs)
        const uint4* Hv2 = (const uint4*)h2p;
        float bA = bias2, bB = 0.f, bC = 0.f, bD = 0.f;
        P2(0,  0,1,2,3,     64,65,66,67,     bA);
        P2(1,  4,5,6,7,     68,69,70,71,     bA);
        P2(2,  8,9,10,11,   72,73,74,75,     bA);
        P2(3,  12,13,14,15, 76,77,78,79,     bA);
        P2(4,  16,17,18,19, 80,81,82,83,     bB);
        P2(5,  20,21,22,23, 84,85,86,87,     bB);
        P2(6,  24,25,26,27, 88,89,90,91,     bB);
        P2(7,  28,29,30,31, 92,93,94,95,     bB);
        P2(8,  32,33,34,35, 96,97,98,99,     bC);
        P2(9,  36,37,38,39, 100,101,102,103, bC);
        P2(10, 40,41,42,43, 104,105,106,107, bC);
        P2(11, 44,45,46,47, 108,109,110,111, bC);
        P2(12, 48,49,50,51, 112,113,114,115, bD);
        P2(13, 52,53,54,55, 116,117,118,119, bD);
        P2(14, 56,57,58,59, 120,121,122,123, bD);
        P2(15, 60,61,62,63, 124,125,126,127, bD);
        float g2 = (bA + bB) + (bC + bD);
        gact[tid] = (sec == 2) ? tanhf_(g2) : sigmoidf_(g2);
        __syncthreads();   // barrier 3

        // ---------- layer-2 state update
        if (tid < HDIM) {
            float gi = gact[tid], gf = gact[tid + 128];
            float gg = gact[tid + 256], go = gact[tid + 384];
            c2 = fmaf(gf, c2, gi * gg);
            float h2 = go * tanhf_(c2);
            ((uint16_t*)h2p)[tid] = f2h(h2);
            h2f[tid] = h2;
        }
        __syncthreads();   // barrier 4

        // ---------- output: out[b,t] = W_out . h2 + b_out   (wave 0 only)
        if (tid < 64) {
            float p = fmaf(wo0, h2f[tid], wo1 * h2f[tid + 64]);
#pragma unroll
            for (int off = 32; off > 0; off >>= 1)
                p += __shfl_down(p, off, 64);
            if (tid == 0) ob[t] = p + bo;
        }
        x_cur = x_nxt;
    }
}

extern "C" void kernel_launch(void* const* d_in, const int* in_sizes, int n_in,
                              void* d_out, int out_size, void* d_ws, size_t ws_size,
                              hipStream_t stream) {
    const float* x     = (const float*)d_in[0];
    const float* W_ih1 = (const float*)d_in[1];
    const float* W_hh1 = (const float*)d_in[2];
    const float* b_ih1 = (const float*)d_in[3];
    const float* b_hh1 = (const float*)d_in[4];
    const float* W_ih2 = (const float*)d_in[5];
    const float* W_hh2 = (const float*)d_in[6];
    const float* b_ih2 = (const float*)d_in[7];
    const float* b_hh2 = (const float*)d_in[8];
    const float* W_out = (const float*)d_in[9];
    const float* b_out = (const float*)d_in[10];
    float* out = (float*)d_out;

    const int B = in_sizes[0] / T_STEPS;   // 256
    hipLaunchKernelGGL(lstm_persistent, dim3(B), dim3(NT), 0, stream,
                       x, W_ih1, W_hh1, b_ih1, b_hh1,
                       W_ih2, W_hh2, b_ih2, b_hh2, W_out, b_out, out);
}